// Round 14
// baseline (211.218 us; speedup 1.0000x reference)
//
#include <hip/hip_runtime.h>

#define N_NODES 50000
#define E_EDGES 800000
#define F_IN    128
#define EDGE_DIM 64
#define HC      256
#define NEG_SLOPE 0.2f

typedef __attribute__((ext_vector_type(8))) short short8;
typedef __attribute__((ext_vector_type(4))) float f32x4;

__device__ __forceinline__ unsigned short f2bf(float f) {
    unsigned u = __builtin_bit_cast(unsigned, f);
    u += 0x7fffu + ((u >> 16) & 1u);
    return (unsigned short)(u >> 16);
}
__device__ __forceinline__ float bf2f(unsigned short b) {
    return __builtin_bit_cast(float, (unsigned)b << 16);
}

// ---------- K_pre: zero counts/gcur, W_T bf16 [256][128], WaT bf16 [16][128], WaE bf16 [16][64] ----------
__global__ __launch_bounds__(256) void k_pre(const float* __restrict__ W,
        const float* __restrict__ att_src, const float* __restrict__ att_dst,
        const float* __restrict__ W_edge, const float* __restrict__ att_edge,
        unsigned short* __restrict__ W_T, unsigned short* __restrict__ WaT,
        unsigned short* __restrict__ WaE, int* __restrict__ counts, int* __restrict__ gcur) {
    int idx = blockIdx.x * 256 + threadIdx.x;
    if (idx < N_NODES) counts[idx] = 0;
    if (idx == 0) *gcur = 0;
    if (idx < 32768) {
        int n = idx >> 7, k = idx & 127;
        W_T[n * 128 + k] = f2bf(W[k * 256 + n]);
    }
    if (idx < 2048) {
        int col = idx & 15, k = idx >> 4;
        const float* att = (col < 8) ? att_src : att_dst;
        int h = col & 7;
        float s = 0.f;
        #pragma unroll
        for (int c = 0; c < 32; ++c)
            s = fmaf(W[k * 256 + h * 32 + c], att[h * 32 + c], s);
        WaT[col * 128 + k] = f2bf(s);
    }
    if (idx < 1024) {    // WaE[c][k]: B-operand for edge-dot MFMA (cols 8..15 zero)
        int c = idx >> 6, k = idx & 63;
        float s = 0.f;
        if (c < 8) {
            #pragma unroll
            for (int cc = 0; cc < 32; ++cc)
                s = fmaf(W_edge[k * 256 + c * 32 + cc], att_edge[c * 32 + cc], s);
        }
        WaE[c * 64 + k] = (c < 8) ? f2bf(s) : (unsigned short)0;
    }
}

// ---------- KA: fused — hist+slot blocks ∥ a-logits mini-MFMA blocks ----------
#define HIST_BLOCKS 782
#define ALOG_BLOCKS 782   // 782*4 waves = 3128 tiles >= 3125
__global__ __launch_bounds__(256) void kA(const float* __restrict__ x,
        const unsigned short* __restrict__ WaT,
        const int4* __restrict__ dst4, int* __restrict__ counts, int4* __restrict__ slot4,
        float* __restrict__ a_src, float* __restrict__ a_dst) {
    int t = threadIdx.x;
    if (blockIdx.x < HIST_BLOCKS) {            // ---- histogram + slot assignment
        int i = blockIdx.x * 256 + t;
        if (i < E_EDGES / 4) {
            int4 d = dst4[i];
            int4 sl;
            sl.x = atomicAdd(&counts[d.x], 1);
            sl.y = atomicAdd(&counts[d.y], 1);
            sl.z = atomicAdd(&counts[d.z], 1);
            sl.w = atomicAdd(&counts[d.w], 1);
            slot4[i] = sl;
        }
        return;
    }
    // ---- a_src/a_dst: one 16-node tile per wave, A-frags direct from global
    int tile = (blockIdx.x - HIST_BLOCKS) * 4 + (t >> 6);
    if (tile >= N_NODES / 16) return;
    int lane = t & 63, mr = lane & 15, g = lane >> 4;
    int node = tile * 16 + mr;                 // A-row this lane loads (< 50000)
    f32x4 acc = (f32x4){0.f, 0.f, 0.f, 0.f};
    #pragma unroll
    for (int ks = 0; ks < 4; ++ks) {
        const float* xp = &x[(size_t)node * 128 + ks * 32 + g * 8];
        short8 a;
        #pragma unroll
        for (int j = 0; j < 8; ++j) a[j] = (short)f2bf(fmaxf(xp[j], 0.f));
        short8 b = *(const short8*)&WaT[mr * 128 + ks * 32 + g * 8];
        acc = __builtin_amdgcn_mfma_f32_16x16x32_bf16(a, b, acc, 0, 0, 0);
    }
    #pragma unroll
    for (int r = 0; r < 4; ++r) {              // C: col=mr, row=g*4+r
        int n2 = tile * 16 + g * 4 + r;
        if (mr < 8) a_src[n2 * 8 + mr]       = acc[r];
        else        a_dst[n2 * 8 + (mr - 8)] = acc[r];
    }
}

// ---------- KB: exclusive-scan counts -> starts via wave scan + global atomic base ----------
__global__ __launch_bounds__(256) void kB_alloc(const int* __restrict__ counts,
                                                int* __restrict__ starts,
                                                int* __restrict__ gcur) {
    int n = blockIdx.x * 256 + threadIdx.x;
    int c = (n < N_NODES) ? counts[n] : 0;
    int incl = c;
    #pragma unroll
    for (int off = 1; off < 64; off <<= 1) {
        int u = __shfl_up(incl, off);
        if ((threadIdx.x & 63) >= off) incl += u;
    }
    int total = __shfl(incl, 63);
    int wavebase = 0;
    if ((threadIdx.x & 63) == 63) wavebase = atomicAdd(gcur, total);
    wavebase = __shfl(wavebase, 63);
    if (n < N_NODES) starts[n] = wavebase + incl - c;
}

// ---------- KC: fused — xs-GEMM MFMA blocks (first) ∥ edge-weight MFMA blocks ----------
#define NT_TILES 782
#define K1_GRID 512
__global__ __launch_bounds__(256, 2) void kC(const float* __restrict__ x,
        const unsigned short* __restrict__ W_T, const unsigned short* __restrict__ WaE,
        const float* __restrict__ ea,
        const int* __restrict__ src, const int* __restrict__ dst,
        const int* __restrict__ slot, const int* __restrict__ starts,
        const float* __restrict__ a_src, const float* __restrict__ a_dst,
        unsigned short* __restrict__ xs,
        _Float16* __restrict__ w_perm, int* __restrict__ src_perm) {
    __shared__ __align__(16) char smem[81920];   // union: GEMM 80KB | edge 3KB
    int t = threadIdx.x;

    if (blockIdx.x >= K1_GRID) {
        // ===== edge-weight part: 256 edges per block =====
        int* s_sn  = (int*)smem;
        int* s_dn  = (int*)(smem + 1024);
        int* s_pos = (int*)(smem + 2048);
        int blockbase = (blockIdx.x - K1_GRID) * 256;
        {
            int e = blockbase + t;
            int dn = dst[e], sn = src[e];
            int pos = starts[dn] + slot[e];
            s_sn[t] = sn; s_dn[t] = dn; s_pos[t] = pos;
            src_perm[pos] = sn;
        }
        __syncthreads();
        int lane = t & 63, w = t >> 6;
        int mr = lane & 15, g = lane >> 4;       // mr = head col, g = k-group
        short8 b0 = *(const short8*)&WaE[mr * 64 + g * 8];
        short8 b1 = *(const short8*)&WaE[mr * 64 + 32 + g * 8];
        #pragma unroll
        for (int ti = 0; ti < 4; ++ti) {
            int lb = w * 64 + ti * 16;
            int er = blockbase + lb + mr;
            const float* ap = &ea[(size_t)er * 64 + g * 8];
            short8 a0, a1;
            #pragma unroll
            for (int j = 0; j < 8; ++j) a0[j] = (short)f2bf(ap[j]);
            #pragma unroll
            for (int j = 0; j < 8; ++j) a1[j] = (short)f2bf(ap[32 + j]);
            f32x4 acc = (f32x4){0.f, 0.f, 0.f, 0.f};
            acc = __builtin_amdgcn_mfma_f32_16x16x32_bf16(a0, b0, acc, 0, 0, 0);
            acc = __builtin_amdgcn_mfma_f32_16x16x32_bf16(a1, b1, acc, 0, 0, 0);
            if (mr < 8) {                        // C: col=head=mr, row=g*4+r
                #pragma unroll
                for (int r = 0; r < 4; ++r) {
                    int le = lb + g * 4 + r;
                    int sn = s_sn[le], dn = s_dn[le];
                    float v = acc[r] + a_src[sn * 8 + mr] + a_dst[dn * 8 + mr];
                    v = (v > 0.f) ? v : NEG_SLOPE * v;
                    w_perm[(size_t)s_pos[le] * 8 + mr] = (_Float16)__expf(v);
                }
            }
        }
        return;
    }

    // ===== xs-GEMM part: blocks 0..511 =====
    unsigned short* sB = (unsigned short*)smem;            // 64 KB
    unsigned short* sA = (unsigned short*)(smem + 65536);  // 16 KB
    for (int G = t; G < 4096; G += 256) {
        int n = G >> 4, gi = G & 15;
        *(int4*)&sB[(n * 16 + (gi ^ (n & 7))) * 8] = *(const int4*)&W_T[n * 128 + gi * 8];
    }
    int lane = t & 63, w = t >> 6, mr = lane & 15, g = lane >> 4;

    bool first = true;
    for (int rt = blockIdx.x; rt < NT_TILES; rt += K1_GRID) {
        if (!first) __syncthreads();
        first = false;
        for (int G = t; G < 1024; G += 256) {
            int r = G >> 4, gi = G & 15;
            int node = rt * 64 + r;
            unsigned short pk[8];
            if (node < N_NODES) {
                const float* xp = &x[(long)node * 128 + gi * 8];
                #pragma unroll
                for (int jj = 0; jj < 8; ++jj) pk[jj] = f2bf(fmaxf(xp[jj], 0.f));
            } else {
                #pragma unroll
                for (int jj = 0; jj < 8; ++jj) pk[jj] = 0;
            }
            *(int4*)&sA[(r * 16 + (gi ^ (r & 7))) * 8] = *(int4*)pk;
        }
        __syncthreads();

        f32x4 acc[16];
        #pragma unroll
        for (int i = 0; i < 16; ++i) acc[i] = (f32x4){0.f, 0.f, 0.f, 0.f};

        int r16 = w * 16 + mr;
        #pragma unroll
        for (int ks = 0; ks < 4; ++ks) {
            int pos = (ks * 4 + g) ^ (mr & 7);
            short8 a = *(const short8*)&sA[(r16 * 16 + pos) * 8];
            #pragma unroll
            for (int nt = 0; nt < 16; ++nt) {
                short8 b = *(const short8*)&sB[((nt * 16 + mr) * 16 + pos) * 8];
                acc[nt] = __builtin_amdgcn_mfma_f32_16x16x32_bf16(a, b, acc[nt], 0, 0, 0);
            }
        }

        #pragma unroll
        for (int r = 0; r < 4; ++r) {
            int node = rt * 64 + w * 16 + g * 4 + r;
            if (node < N_NODES) {
                #pragma unroll
                for (int nt = 0; nt < 16; ++nt)
                    xs[(long)node * 256 + nt * 16 + mr] = f2bf(acc[nt][r]);
            }
        }
    }
}

// ---------- K6: wave-per-node streaming normalize + aggregation (fp16 weights) ----------
__global__ __launch_bounds__(256) void k6_wave(
    const int* __restrict__ starts, const int* __restrict__ counts,
    const _Float16* __restrict__ w_perm, const int* __restrict__ src_perm,
    const unsigned short* __restrict__ xs, const float* __restrict__ bias,
    float* __restrict__ out) {
    int lane = threadIdx.x & 63;
    int n = blockIdx.x * 4 + (threadIdx.x >> 6);
    if (n >= N_NODES) return;
    int start = starts[n], cnt = counts[n];
    int j = lane >> 3;        // weight-slot this lane loads
    int hq = lane >> 3;       // head of this lane's 4 output cols (c = lane*4+k)

    float acc0 = 0.f, acc1 = 0.f, acc2 = 0.f, acc3 = 0.f;
    float psum = 0.f;
    for (int base = 0; base < cnt; base += 8) {
        int nk = cnt - base; if (nk > 8) nk = 8;
        float wv = (float)w_perm[(size_t)(start + base) * 8 + lane];   // 128B coalesced
        if (j >= nk) wv = 0.f;
        psum += wv;
        int sv = src_perm[start + base + (lane & 7)];
        #pragma unroll
        for (int jj = 0; jj < 8; ++jj) {
            int s = __shfl(sv, jj);
            s = (jj < nk) ? s : 0;
            float w = __shfl(wv, jj * 8 + hq);
            ushort4 xv = *(const ushort4*)&xs[(size_t)s * 256 + lane * 4];
            acc0 = fmaf(w, bf2f(xv.x), acc0);
            acc1 = fmaf(w, bf2f(xv.y), acc1);
            acc2 = fmaf(w, bf2f(xv.z), acc2);
            acc3 = fmaf(w, bf2f(xv.w), acc3);
        }
    }
    psum += __shfl_xor(psum, 8);
    psum += __shfl_xor(psum, 16);
    psum += __shfl_xor(psum, 32);
    float denom = __shfl(psum, hq);
    float rinv = 1.0f / (denom + 1e-16f);
    float4 bv = *(const float4*)&bias[lane * 4];
    f32x4 o;
    o[0] = acc0 * rinv + bv.x;
    o[1] = acc1 * rinv + bv.y;
    o[2] = acc2 * rinv + bv.z;
    o[3] = acc3 * rinv + bv.w;
    __builtin_nontemporal_store(o, (f32x4*)&out[(size_t)n * 256 + lane * 4]);
}

extern "C" void kernel_launch(void* const* d_in, const int* in_sizes, int n_in,
                              void* d_out, int out_size, void* d_ws, size_t ws_size,
                              hipStream_t stream) {
    const float* x         = (const float*)d_in[0];
    const int*   ei        = (const int*)d_in[1];   // [2,E]: src = ei, dst = ei+E
    const float* edge_attr = (const float*)d_in[2];
    const float* W         = (const float*)d_in[3];
    const float* att_src   = (const float*)d_in[4];
    const float* att_dst   = (const float*)d_in[5];
    const float* W_edge    = (const float*)d_in[6];
    const float* att_edge  = (const float*)d_in[7];
    const float* bias      = (const float*)d_in[8];
    float* out = (float*)d_out;

    const int* e_src = ei;
    const int* e_dst = ei + E_EDGES;

    char* p = (char*)d_ws;
    unsigned short* xs = (unsigned short*)p; p += (size_t)N_NODES * HC * 2;    // 25.6 MB
    float* a_src   = (float*)p; p += (size_t)N_NODES * 8 * 4;                  // 1.6 MB
    float* a_dst   = (float*)p; p += (size_t)N_NODES * 8 * 4;                  // 1.6 MB
    _Float16* w_perm = (_Float16*)p; p += (size_t)E_EDGES * 8 * 2 + 256;       // 12.8 MB (+pad)
    int* src_perm  = (int*)p;   p += (size_t)E_EDGES * 4 + 256;                // 3.2 MB (+pad)
    int* slot      = (int*)p;   p += (size_t)E_EDGES * 4 + 256;                // 3.2 MB (+pad)
    unsigned short* W_T  = (unsigned short*)p; p += 32768 * 2;                 // 64 KB
    unsigned short* WaT  = (unsigned short*)p; p += 2048 * 2;                  // 4 KB
    unsigned short* WaE  = (unsigned short*)p; p += 1024 * 2;                  // 2 KB
    int* counts    = (int*)p;   p += 200192;
    int* starts    = (int*)p;   p += 200192;
    int* gcur      = (int*)p;   p += 256;

    hipLaunchKernelGGL(k_pre, dim3(196), dim3(256), 0, stream,
                       W, att_src, att_dst, W_edge, att_edge, W_T, WaT, WaE, counts, gcur);
    hipLaunchKernelGGL(kA, dim3(HIST_BLOCKS + ALOG_BLOCKS), dim3(256), 0, stream,
                       x, WaT, (const int4*)e_dst, counts, (int4*)slot, a_src, a_dst);
    hipLaunchKernelGGL(kB_alloc, dim3(196), dim3(256), 0, stream,
                       counts, starts, gcur);
    hipLaunchKernelGGL(kC, dim3(K1_GRID + E_EDGES / 256), dim3(256), 0, stream,
                       x, W_T, WaE, edge_attr, e_src, e_dst, slot, starts,
                       a_src, a_dst, xs, w_perm, src_perm);
    hipLaunchKernelGGL(k6_wave, dim3(N_NODES / 4), dim3(256), 0, stream,
                       starts, counts, w_perm, src_perm, xs, bias, out);
}

// Round 15
// 209.948 us; speedup vs baseline: 1.0060x; 1.0060x over previous
//
#include <hip/hip_runtime.h>

#define N_NODES 50000
#define E_EDGES 800000
#define F_IN    128
#define EDGE_DIM 64
#define HC      256
#define NEG_SLOPE 0.2f

typedef __attribute__((ext_vector_type(8))) short short8;
typedef __attribute__((ext_vector_type(4))) float f32x4;

__device__ __forceinline__ unsigned short f2bf(float f) {
    unsigned u = __builtin_bit_cast(unsigned, f);
    u += 0x7fffu + ((u >> 16) & 1u);
    return (unsigned short)(u >> 16);
}
__device__ __forceinline__ float bf2f(unsigned short b) {
    return __builtin_bit_cast(float, (unsigned)b << 16);
}

// ---------- K_pre: zero counts/gcur, W_T bf16 [256][128], WaT bf16 [16][128], WaE bf16 [16][64] ----------
__global__ __launch_bounds__(256) void k_pre(const float* __restrict__ W,
        const float* __restrict__ att_src, const float* __restrict__ att_dst,
        const float* __restrict__ W_edge, const float* __restrict__ att_edge,
        unsigned short* __restrict__ W_T, unsigned short* __restrict__ WaT,
        unsigned short* __restrict__ WaE, int* __restrict__ counts, int* __restrict__ gcur) {
    int idx = blockIdx.x * 256 + threadIdx.x;
    if (idx < N_NODES) counts[idx] = 0;
    if (idx == 0) *gcur = 0;
    if (idx < 32768) {
        int n = idx >> 7, k = idx & 127;
        W_T[n * 128 + k] = f2bf(W[k * 256 + n]);
    }
    if (idx < 2048) {
        int col = idx & 15, k = idx >> 4;
        const float* att = (col < 8) ? att_src : att_dst;
        int h = col & 7;
        float s = 0.f;
        #pragma unroll
        for (int c = 0; c < 32; ++c)
            s = fmaf(W[k * 256 + h * 32 + c], att[h * 32 + c], s);
        WaT[col * 128 + k] = f2bf(s);
    }
    if (idx < 1024) {    // WaE[c][k]: B-operand for edge-dot MFMA (cols 8..15 zero)
        int c = idx >> 6, k = idx & 63;
        float s = 0.f;
        if (c < 8) {
            #pragma unroll
            for (int cc = 0; cc < 32; ++cc)
                s = fmaf(W_edge[k * 256 + c * 32 + cc], att_edge[c * 32 + cc], s);
        }
        WaE[c * 64 + k] = (c < 8) ? f2bf(s) : (unsigned short)0;
    }
}

// ---------- KA: fused — hist+slot blocks ∥ a-logits mini-MFMA blocks ----------
#define HIST_BLOCKS 782
#define ALOG_BLOCKS 782   // 782*4 waves = 3128 tiles >= 3125
__global__ __launch_bounds__(256) void kA(const float* __restrict__ x,
        const unsigned short* __restrict__ WaT,
        const int4* __restrict__ dst4, int* __restrict__ counts, int4* __restrict__ slot4,
        float* __restrict__ a_src, float* __restrict__ a_dst) {
    int t = threadIdx.x;
    if (blockIdx.x < HIST_BLOCKS) {            // ---- histogram + slot assignment
        int i = blockIdx.x * 256 + t;
        if (i < E_EDGES / 4) {
            int4 d = dst4[i];
            int4 sl;
            sl.x = atomicAdd(&counts[d.x], 1);
            sl.y = atomicAdd(&counts[d.y], 1);
            sl.z = atomicAdd(&counts[d.z], 1);
            sl.w = atomicAdd(&counts[d.w], 1);
            slot4[i] = sl;
        }
        return;
    }
    // ---- a_src/a_dst: one 16-node tile per wave, A-frags direct from global
    int tile = (blockIdx.x - HIST_BLOCKS) * 4 + (t >> 6);
    if (tile >= N_NODES / 16) return;
    int lane = t & 63, mr = lane & 15, g = lane >> 4;
    int node = tile * 16 + mr;                 // A-row this lane loads (< 50000)
    f32x4 acc = (f32x4){0.f, 0.f, 0.f, 0.f};
    #pragma unroll
    for (int ks = 0; ks < 4; ++ks) {
        const float* xp = &x[(size_t)node * 128 + ks * 32 + g * 8];
        short8 a;
        #pragma unroll
        for (int j = 0; j < 8; ++j) a[j] = (short)f2bf(fmaxf(xp[j], 0.f));
        short8 b = *(const short8*)&WaT[mr * 128 + ks * 32 + g * 8];
        acc = __builtin_amdgcn_mfma_f32_16x16x32_bf16(a, b, acc, 0, 0, 0);
    }
    #pragma unroll
    for (int r = 0; r < 4; ++r) {              // C: col=mr, row=g*4+r
        int n2 = tile * 16 + g * 4 + r;
        if (mr < 8) a_src[n2 * 8 + mr]       = acc[r];
        else        a_dst[n2 * 8 + (mr - 8)] = acc[r];
    }
}

// ---------- KB: exclusive-scan counts -> starts via wave scan + global atomic base ----------
__global__ __launch_bounds__(256) void kB_alloc(const int* __restrict__ counts,
                                                int* __restrict__ starts,
                                                int* __restrict__ gcur) {
    int n = blockIdx.x * 256 + threadIdx.x;
    int c = (n < N_NODES) ? counts[n] : 0;
    int incl = c;
    #pragma unroll
    for (int off = 1; off < 64; off <<= 1) {
        int u = __shfl_up(incl, off);
        if ((threadIdx.x & 63) >= off) incl += u;
    }
    int total = __shfl(incl, 63);
    int wavebase = 0;
    if ((threadIdx.x & 63) == 63) wavebase = atomicAdd(gcur, total);
    wavebase = __shfl(wavebase, 63);
    if (n < N_NODES) starts[n] = wavebase + incl - c;
}

// ---------- KC-v2: fused — xs-GEMM (32KB LDS, A-direct, col-halved B) ∥ edge-weight MFMA ----------
#define NT_TILES 782
#define GEMM_BLOCKS 512    // bid>>8 = col-half, bid&255 = row-tile start (stride 256)
__global__ __launch_bounds__(256) void kC(const float* __restrict__ x,
        const unsigned short* __restrict__ W_T, const unsigned short* __restrict__ WaE,
        const float* __restrict__ ea,
        const int* __restrict__ src, const int* __restrict__ dst,
        const int* __restrict__ slot, const int* __restrict__ starts,
        const float* __restrict__ a_src, const float* __restrict__ a_dst,
        unsigned short* __restrict__ xs,
        _Float16* __restrict__ w_perm, int* __restrict__ src_perm) {
    __shared__ __align__(16) char smem[32768];   // union: GEMM sB 32KB | edge 3KB
    int t = threadIdx.x;

    if (blockIdx.x >= GEMM_BLOCKS) {
        // ===== edge-weight part: 256 edges per block =====
        int* s_sn  = (int*)smem;
        int* s_dn  = (int*)(smem + 1024);
        int* s_pos = (int*)(smem + 2048);
        int blockbase = (blockIdx.x - GEMM_BLOCKS) * 256;
        {
            int e = blockbase + t;
            int dn = dst[e], sn = src[e];
            int pos = starts[dn] + slot[e];
            s_sn[t] = sn; s_dn[t] = dn; s_pos[t] = pos;
            src_perm[pos] = sn;
        }
        __syncthreads();
        int lane = t & 63, w = t >> 6;
        int mr = lane & 15, g = lane >> 4;       // mr = head col, g = k-group
        short8 b0 = *(const short8*)&WaE[mr * 64 + g * 8];
        short8 b1 = *(const short8*)&WaE[mr * 64 + 32 + g * 8];
        #pragma unroll
        for (int ti = 0; ti < 4; ++ti) {
            int lb = w * 64 + ti * 16;
            int er = blockbase + lb + mr;
            const float* ap = &ea[(size_t)er * 64 + g * 8];
            short8 a0, a1;
            #pragma unroll
            for (int j = 0; j < 8; ++j) a0[j] = (short)f2bf(ap[j]);
            #pragma unroll
            for (int j = 0; j < 8; ++j) a1[j] = (short)f2bf(ap[32 + j]);
            f32x4 acc = (f32x4){0.f, 0.f, 0.f, 0.f};
            acc = __builtin_amdgcn_mfma_f32_16x16x32_bf16(a0, b0, acc, 0, 0, 0);
            acc = __builtin_amdgcn_mfma_f32_16x16x32_bf16(a1, b1, acc, 0, 0, 0);
            if (mr < 8) {                        // C: col=head=mr, row=g*4+r
                #pragma unroll
                for (int r = 0; r < 4; ++r) {
                    int le = lb + g * 4 + r;
                    int sn = s_sn[le], dn = s_dn[le];
                    float v = acc[r] + a_src[sn * 8 + mr] + a_dst[dn * 8 + mr];
                    v = (v > 0.f) ? v : NEG_SLOPE * v;
                    w_perm[(size_t)s_pos[le] * 8 + mr] = (_Float16)__expf(v);
                }
            }
        }
        return;
    }

    // ===== xs-GEMM part: blocks 0..511; ch = bid>>8 fixed per block =====
    unsigned short* sB = (unsigned short*)smem;            // 128 cols x 128 k = 32 KB
    int ch = blockIdx.x >> 8;                  // column half: cols ch*128..+128
    int rt0 = blockIdx.x & 255;
    // stage B half: rows nn = 0..127 of W_T[ch*128 + nn]
    for (int G = t; G < 2048; G += 256) {
        int nn = G >> 4, gi = G & 15;
        *(int4*)&sB[(nn * 16 + (gi ^ (nn & 7))) * 8] =
            *(const int4*)&W_T[(ch * 128 + nn) * 128 + gi * 8];
    }
    __syncthreads();
    int lane = t & 63, w = t >> 6, mr = lane & 15, g = lane >> 4;

    for (int rt = rt0; rt < NT_TILES; rt += 256) {
        // A-fragments direct from global (relu+cvt in registers)
        int node = rt * 64 + w * 16 + mr;
        short8 a[4];
        if (node < N_NODES) {
            #pragma unroll
            for (int ks = 0; ks < 4; ++ks) {
                const float* xp = &x[(size_t)node * 128 + ks * 32 + g * 8];
                #pragma unroll
                for (int j = 0; j < 8; ++j) a[ks][j] = (short)f2bf(fmaxf(xp[j], 0.f));
            }
        } else {
            #pragma unroll
            for (int ks = 0; ks < 4; ++ks)
                #pragma unroll
                for (int j = 0; j < 8; ++j) a[ks][j] = 0;
        }

        f32x4 acc[8];
        #pragma unroll
        for (int i = 0; i < 8; ++i) acc[i] = (f32x4){0.f, 0.f, 0.f, 0.f};

        #pragma unroll
        for (int ks = 0; ks < 4; ++ks) {
            int pos = (ks * 4 + g) ^ (mr & 7);
            #pragma unroll
            for (int nt = 0; nt < 8; ++nt) {
                short8 b = *(const short8*)&sB[((nt * 16 + mr) * 16 + pos) * 8];
                acc[nt] = __builtin_amdgcn_mfma_f32_16x16x32_bf16(a[ks], b, acc[nt], 0, 0, 0);
            }
        }

        #pragma unroll
        for (int r = 0; r < 4; ++r) {
            int node2 = rt * 64 + w * 16 + g * 4 + r;
            if (node2 < N_NODES) {
                #pragma unroll
                for (int nt = 0; nt < 8; ++nt)
                    xs[(size_t)node2 * 256 + ch * 128 + nt * 16 + mr] = f2bf(acc[nt][r]);
            }
        }
    }
}

// ---------- K6: wave-per-node streaming normalize + aggregation (fp16 weights) ----------
__global__ __launch_bounds__(256) void k6_wave(
    const int* __restrict__ starts, const int* __restrict__ counts,
    const _Float16* __restrict__ w_perm, const int* __restrict__ src_perm,
    const unsigned short* __restrict__ xs, const float* __restrict__ bias,
    float* __restrict__ out) {
    int lane = threadIdx.x & 63;
    int n = blockIdx.x * 4 + (threadIdx.x >> 6);
    if (n >= N_NODES) return;
    int start = starts[n], cnt = counts[n];
    int j = lane >> 3;        // weight-slot this lane loads
    int hq = lane >> 3;       // head of this lane's 4 output cols (c = lane*4+k)

    float acc0 = 0.f, acc1 = 0.f, acc2 = 0.f, acc3 = 0.f;
    float psum = 0.f;
    for (int base = 0; base < cnt; base += 8) {
        int nk = cnt - base; if (nk > 8) nk = 8;
        float wv = (float)w_perm[(size_t)(start + base) * 8 + lane];   // 128B coalesced
        if (j >= nk) wv = 0.f;
        psum += wv;
        int sv = src_perm[start + base + (lane & 7)];
        #pragma unroll
        for (int jj = 0; jj < 8; ++jj) {
            int s = __shfl(sv, jj);
            s = (jj < nk) ? s : 0;
            float w = __shfl(wv, jj * 8 + hq);
            ushort4 xv = *(const ushort4*)&xs[(size_t)s * 256 + lane * 4];
            acc0 = fmaf(w, bf2f(xv.x), acc0);
            acc1 = fmaf(w, bf2f(xv.y), acc1);
            acc2 = fmaf(w, bf2f(xv.z), acc2);
            acc3 = fmaf(w, bf2f(xv.w), acc3);
        }
    }
    psum += __shfl_xor(psum, 8);
    psum += __shfl_xor(psum, 16);
    psum += __shfl_xor(psum, 32);
    float denom = __shfl(psum, hq);
    float rinv = 1.0f / (denom + 1e-16f);
    float4 bv = *(const float4*)&bias[lane * 4];
    f32x4 o;
    o[0] = acc0 * rinv + bv.x;
    o[1] = acc1 * rinv + bv.y;
    o[2] = acc2 * rinv + bv.z;
    o[3] = acc3 * rinv + bv.w;
    __builtin_nontemporal_store(o, (f32x4*)&out[(size_t)n * 256 + lane * 4]);
}

extern "C" void kernel_launch(void* const* d_in, const int* in_sizes, int n_in,
                              void* d_out, int out_size, void* d_ws, size_t ws_size,
                              hipStream_t stream) {
    const float* x         = (const float*)d_in[0];
    const int*   ei        = (const int*)d_in[1];   // [2,E]: src = ei, dst = ei+E
    const float* edge_attr = (const float*)d_in[2];
    const float* W         = (const float*)d_in[3];
    const float* att_src   = (const float*)d_in[4];
    const float* att_dst   = (const float*)d_in[5];
    const float* W_edge    = (const float*)d_in[6];
    const float* att_edge  = (const float*)d_in[7];
    const float* bias      = (const float*)d_in[8];
    float* out = (float*)d_out;

    const int* e_src = ei;
    const int* e_dst = ei + E_EDGES;

    char* p = (char*)d_ws;
    unsigned short* xs = (unsigned short*)p; p += (size_t)N_NODES * HC * 2;    // 25.6 MB
    float* a_src   = (float*)p; p += (size_t)N_NODES * 8 * 4;                  // 1.6 MB
    float* a_dst   = (float*)p; p += (size_t)N_NODES * 8 * 4;                  // 1.6 MB
    _Float16* w_perm = (_Float16*)p; p += (size_t)E_EDGES * 8 * 2 + 256;       // 12.8 MB (+pad)
    int* src_perm  = (int*)p;   p += (size_t)E_EDGES * 4 + 256;                // 3.2 MB (+pad)
    int* slot      = (int*)p;   p += (size_t)E_EDGES * 4 + 256;                // 3.2 MB (+pad)
    unsigned short* W_T  = (unsigned short*)p; p += 32768 * 2;                 // 64 KB
    unsigned short* WaT  = (unsigned short*)p; p += 2048 * 2;                  // 4 KB
    unsigned short* WaE  = (unsigned short*)p; p += 1024 * 2;                  // 2 KB
    int* counts    = (int*)p;   p += 200192;
    int* starts    = (int*)p;   p += 200192;
    int* gcur      = (int*)p;   p += 256;

    hipLaunchKernelGGL(k_pre, dim3(196), dim3(256), 0, stream,
                       W, att_src, att_dst, W_edge, att_edge, W_T, WaT, WaE, counts, gcur);
    hipLaunchKernelGGL(kA, dim3(HIST_BLOCKS + ALOG_BLOCKS), dim3(256), 0, stream,
                       x, WaT, (const int4*)e_dst, counts, (int4*)slot, a_src, a_dst);
    hipLaunchKernelGGL(kB_alloc, dim3(196), dim3(256), 0, stream,
                       counts, starts, gcur);
    hipLaunchKernelGGL(kC, dim3(GEMM_BLOCKS + E_EDGES / 256), dim3(256), 0, stream,
                       x, W_T, WaE, edge_attr, e_src, e_dst, slot, starts,
                       a_src, a_dst, xs, w_perm, src_perm);
    hipLaunchKernelGGL(k6_wave, dim3(N_NODES / 4), dim3(256), 0, stream,
                       starts, counts, w_perm, src_perm, xs, bias, out);
}